// Round 8
// baseline (56.088 us; speedup 1.0000x reference)
//
#include <hip/hip_runtime.h>

#define HH 128
#define NN 64
#define LL 256
#define WPITCH 264   // u16 pitch of WT rows

typedef __attribute__((ext_vector_type(8))) short bf8;
typedef __attribute__((ext_vector_type(4))) float f32x4;

__device__ inline ushort f2bf(float f) {
    uint x = __float_as_uint(f);
    return (ushort)((x + 0x7fffu + ((x >> 16) & 1u)) >> 16);
}
__device__ inline uint cvt_pk_bf16(float lo, float hi) {
    uint r;
    asm volatile("v_cvt_pk_bf16_f32 %0, %1, %2" : "=v"(r) : "v"(lo), "v"(hi));
    return r;
}
#define MFMA(a,b,c) __builtin_amdgcn_mfma_f32_16x16x32_bf16((a),(b),(c),0,0,0)

// Tap generation, hw trig, one block per (h, s). Packed pair-table out:
// arrg[(s*HH+h)*512 + i] = rev[i] | rev[i+1]<<16, rev[i] = kcat_s[h][511-i].
__global__ __launch_bounds__(512) void ssm_gen_fast(
    const float* __restrict__ A_re0, const float* __restrict__ A_im0,
    const float* __restrict__ C_re0, const float* __restrict__ C_im0,
    const float* __restrict__ log_dt0,
    const float* __restrict__ A_re1, const float* __restrict__ A_im1,
    const float* __restrict__ C_re1, const float* __restrict__ C_im1,
    const float* __restrict__ log_dt1,
    uint* __restrict__ arrg)
{
    __shared__ float4 par[128];     // (ch,n) -> {xr, xi_rev, Kr2, Ki2}
    __shared__ ushort rev[512];

    int tid = threadIdx.x;
    int h   = blockIdx.x;
    int s   = blockIdx.y;

    if (tid < 128) {
        int n  = tid & 63;
        int ch = tid >> 6;
        const float* Ar = s ? A_re1 : A_re0;
        const float* Ai = s ? A_im1 : A_im0;
        const float* Cr = s ? C_re1 : C_re0;
        const float* Ci = s ? C_im1 : C_im0;
        const float* Ld = s ? log_dt1 : log_dt0;
        float dt = __expf(Ld[h]);
        float ar = Ar[h*NN + n], ai = Ai[h*NN + n];
        float cr = Cr[(ch*HH + h)*NN + n], ci = Ci[(ch*HH + h)*NN + n];
        float xr = dt * ar, xi = dt * ai;
        float phr = xi * 0.15915494f;
        float phf = phr - floorf(phr);
        float sn = __sinf(6.2831853f * phf);
        float cs = __cosf(6.2831853f * phf);
        float e  = __expf(xr);
        float er = e*cs - 1.f, ei = e*sn;
        float inv = 1.f / (ar*ar + ai*ai);
        float dr = (er*ar + ei*ai) * inv;
        float di = (ei*ar - er*ai) * inv;
        float Kr = 2.f*(cr*dr - ci*di);
        float Ki = 2.f*(cr*di + ci*dr);
        par[tid] = (float4){ xr, xi * 0.15915494f, Kr, Ki };
    }
    __syncthreads();

    {
        int l  = tid & 255;
        int ch = tid >> 8;
        float lf = (float)l;
        int ri = ch ? (256 + l) : (255 - l);
        const float4* pb = &par[ch*64];
        float acc = 0.f;
        for (int n = 0; n < NN; ++n) {
            float4 p = pb[n];
            float mag = __expf(p.x * lf);
            float ph  = p.y * lf;
            float phf = ph - floorf(ph);
            float ang = 6.2831853f * phf;
            acc += p.z * (mag * __cosf(ang)) - p.w * (mag * __sinf(ang));
        }
        rev[ri] = f2bf(acc);
    }
    __syncthreads();

    uint lo = rev[tid];
    uint hi = (tid < 511) ? (uint)rev[tid + 1] : 0u;
    arrg[(s*HH + h)*512 + tid] = lo | (hi << 16);
}

// Fused S4ND per (b, h, y'-quarter): 256 threads / 4 waves, 4 blocks/CU.
// phase 1: WT[y'][x] = sum_y M2[y'][y]*U[x][y]  (acc in regs, WT in LDS)
// phase 2: Y[x'][y'] = sum_x M1[x'][x]*WT[y'][x] + D[h]*u -> global.
__global__ __launch_bounds__(256, 4) void s4nd_one(
    const float* __restrict__ u, const float* __restrict__ Dv,
    const uint* __restrict__ arrg, float* __restrict__ out)
{
    __shared__ ushort WT[64 * WPITCH];    // 33792 B
    __shared__ uint   arr[2][512];        // 4096 B

    int tid = threadIdx.x;

    // XCD swizzle: all 4 quarter-blocks of a bh on the same XCD, adjacent.
    int j    = blockIdx.x;
    int xcd  = j & 7;
    int k    = j >> 3;
    int bh   = xcd * 32 + (k >> 2);
    int yq   = (k & 3) * 64;              // y' quarter offset
    int h    = bh & (HH - 1);

#pragma unroll
    for (int i = 0; i < 2; ++i)
        arr[i][tid]       = arrg[(i*HH + h)*512 + tid];
#pragma unroll
    for (int i = 0; i < 2; ++i)
        arr[i][tid + 256] = arrg[(i*HH + h)*512 + tid + 256];
    __syncthreads();

    int lane = tid & 63;
    int w = tid >> 6;                 // 0..3
    int c = lane & 15, q = lane >> 4;

    f32x4 acc[16];
#pragma unroll
    for (int i = 0; i < 16; ++i) acc[i] = (f32x4){0.f,0.f,0.f,0.f};

    const float* ub = u + (size_t)bh * LL * LL;

    // ---- phase 1 (no barriers): wave w covers x in [w*64, w*64+64) ----
    // acc[mi*4+rr]: mi = y'16-block (4), rr = x 16-block (4)
    {
        const float* rp0 = ub + (size_t)(w*64 +  0 + c) * LL;
        const float* rp1 = ub + (size_t)(w*64 + 16 + c) * LL;
        const float* rp2 = ub + (size_t)(w*64 + 32 + c) * LL;
        const float* rp3 = ub + (size_t)(w*64 + 48 + c) * LL;
#pragma unroll 2
        for (int kk = 0; kk < 8; ++kk) {
            int yb = kk*32 + 8*q;
            float4 f0a = *(const float4*)(rp0 + yb), f0b = *(const float4*)(rp0 + yb + 4);
            float4 f1a = *(const float4*)(rp1 + yb), f1b = *(const float4*)(rp1 + yb + 4);
            float4 f2a = *(const float4*)(rp2 + yb), f2b = *(const float4*)(rp2 + yb + 4);
            float4 f3a = *(const float4*)(rp3 + yb), f3b = *(const float4*)(rp3 + yb + 4);
            bf8 b0, b1, b2, b3;
            uint* p0 = (uint*)&b0; uint* p1 = (uint*)&b1;
            uint* p2 = (uint*)&b2; uint* p3 = (uint*)&b3;
            p0[0] = cvt_pk_bf16(f0a.x, f0a.y); p0[1] = cvt_pk_bf16(f0a.z, f0a.w);
            p0[2] = cvt_pk_bf16(f0b.x, f0b.y); p0[3] = cvt_pk_bf16(f0b.z, f0b.w);
            p1[0] = cvt_pk_bf16(f1a.x, f1a.y); p1[1] = cvt_pk_bf16(f1a.z, f1a.w);
            p1[2] = cvt_pk_bf16(f1b.x, f1b.y); p1[3] = cvt_pk_bf16(f1b.z, f1b.w);
            p2[0] = cvt_pk_bf16(f2a.x, f2a.y); p2[1] = cvt_pk_bf16(f2a.z, f2a.w);
            p2[2] = cvt_pk_bf16(f2b.x, f2b.y); p2[3] = cvt_pk_bf16(f2b.z, f2b.w);
            p3[0] = cvt_pk_bf16(f3a.x, f3a.y); p3[1] = cvt_pk_bf16(f3a.z, f3a.w);
            p3[2] = cvt_pk_bf16(f3b.x, f3b.y); p3[3] = cvt_pk_bf16(f3b.z, f3b.w);
            int sbase = 255 - yq - c + kk*32 + 8*q;
            __builtin_amdgcn_s_setprio(1);
#pragma unroll
            for (int mi = 0; mi < 4; ++mi) {
                int s0 = sbase - 16*mi;   // a[jj] = M2[yq+16mi+c][kk*32+8q+jj]
                bf8 a; uint* pa = (uint*)&a;
                pa[0] = arr[1][s0];     pa[1] = arr[1][s0 + 2];
                pa[2] = arr[1][s0 + 4]; pa[3] = arr[1][s0 + 6];
                acc[mi*4 + 0] = MFMA(a, b0, acc[mi*4 + 0]);
                acc[mi*4 + 1] = MFMA(a, b1, acc[mi*4 + 1]);
                acc[mi*4 + 2] = MFMA(a, b2, acc[mi*4 + 2]);
                acc[mi*4 + 3] = MFMA(a, b3, acc[mi*4 + 3]);
            }
            __builtin_amdgcn_s_setprio(0);
        }
    }

    // ---- acc -> WT (bf16, XOR-swizzled columns), rows are quarter-local ----
#pragma unroll
    for (int mi = 0; mi < 4; ++mi)
#pragma unroll
        for (int rr = 0; rr < 4; ++rr)
#pragma unroll
            for (int r = 0; r < 4; ++r) {
                int row = 16*mi + 4*q + r;
                int col = (w*64 + 16*rr + c) ^ ((row & 7) << 3);
                WT[row*WPITCH + col] = f2bf(acc[mi*4 + rr][r]);
                acc[mi*4 + rr][r] = 0.f;
            }
    __syncthreads();

    // ---- phase 2 (no barriers): wave w -> x' in [w*64, w*64+64) ----
    {
        int wm2 = w * 64;
#pragma unroll 2
        for (int kk = 0; kk < 8; ++kk) {
            int xb = kk*32;
            bf8 b[4];
#pragma unroll
            for (int ni = 0; ni < 4; ++ni) {
                int row = 16*ni + c;
                int col = (xb + 8*q) ^ ((row & 7) << 3);
                b[ni] = *(const bf8*)&WT[row*WPITCH + col];
            }
            int sbase = 255 - wm2 - c + xb + 8*q;
            __builtin_amdgcn_s_setprio(1);
#pragma unroll
            for (int mi = 0; mi < 4; ++mi) {
                int s0 = sbase - 16*mi;  // a[jj] = M1[wm2+16mi+c][xb+8q+jj]
                bf8 a; uint* pa = (uint*)&a;
                pa[0] = arr[0][s0];     pa[1] = arr[0][s0 + 2];
                pa[2] = arr[0][s0 + 4]; pa[3] = arr[0][s0 + 6];
#pragma unroll
                for (int ni = 0; ni < 4; ++ni)
                    acc[mi*4 + ni] = MFMA(a, b[ni], acc[mi*4 + ni]);
            }
            __builtin_amdgcn_s_setprio(0);
        }

        // ---- epilogue: Y + D*u -> global ----
        float dh = Dv[h];
        float* yb_ = out + (size_t)bh * LL * LL;
#pragma unroll
        for (int mi = 0; mi < 4; ++mi)
#pragma unroll
            for (int ni = 0; ni < 4; ++ni)
#pragma unroll
                for (int r = 0; r < 4; ++r) {
                    int row = wm2 + 16*mi + 4*q + r;
                    int col = yq + 16*ni + c;
                    size_t o = (size_t)row * LL + col;
                    yb_[o] = acc[mi*4 + ni][r] + dh * ub[o];
                }
    }
}

extern "C" void kernel_launch(void* const* d_in, const int* in_sizes, int n_in,
                              void* d_out, int out_size, void* d_ws, size_t ws_size,
                              hipStream_t stream)
{
    const float* u       = (const float*)d_in[0];
    const float* D       = (const float*)d_in[1];
    const float* A_re0   = (const float*)d_in[2];
    const float* A_im0   = (const float*)d_in[3];
    const float* C_re0   = (const float*)d_in[4];
    const float* C_im0   = (const float*)d_in[5];
    const float* log_dt0 = (const float*)d_in[6];
    const float* A_re1   = (const float*)d_in[7];
    const float* A_im1   = (const float*)d_in[8];
    const float* C_re1   = (const float*)d_in[9];
    const float* C_im1   = (const float*)d_in[10];
    const float* log_dt1 = (const float*)d_in[11];
    float* out = (float*)d_out;

    uint* arrg = (uint*)d_ws;   // 2*128*512 u32 = 512 KB

    ssm_gen_fast<<<dim3(HH, 2), 512, 0, stream>>>(
        A_re0, A_im0, C_re0, C_im0, log_dt0,
        A_re1, A_im1, C_re1, C_im1, log_dt1, arrg);
    s4nd_one<<<1024, 256, 0, stream>>>(u, D, arrg, out);
}